// Round 1
// baseline (1103.003 us; speedup 1.0000x reference)
//
#include <hip/hip_runtime.h>
#include <math.h>

#define ROWS 100352        // B * NW * N = 2*512*98
#define EPSL 1e-5f
#define SCALE_Q 0.17677669529663687f   // 32^-0.5

// partition-row -> x flat spatial index (applies shift): row r with window coords
// (b, zd,zh,zw, td,th,tw) reads/writes x at (b, (d+1)%16, (h+3)%56, (w+3)%56)
__device__ __forceinline__ size_t map_row(int r) {
  int t = r;
  int tw = t % 7; t /= 7;
  int th = t % 7; t /= 7;
  int td = t & 1;  t >>= 1;
  int zw = t & 7;  t >>= 3;
  int zh = t & 7;  t >>= 3;
  int zd = t & 7;  int bb = t >> 3;
  int d = zd * 2 + td;
  int h = zh * 7 + th;
  int w = zw * 7 + tw;
  int sd = (d + 1) & 15;
  int sh = h + 3; if (sh >= 56) sh -= 56;
  int sw = w + 3; if (sw >= 56) sw -= 56;
  return ((size_t)((bb * 16 + sd) * 56 + sh)) * 56 + sw;
}

// LayerNorm over C=128. shifted=1: out[r] = LN(x[map_row(r)]) (gather+partition)
// shifted=0: out[r] = LN(x[r]). 32 lanes per row, 8 rows per block.
__global__ __launch_bounds__(256) void k_ln(
    const float* __restrict__ x, const float* __restrict__ g,
    const float* __restrict__ b, float* __restrict__ out, int shifted)
{
  int tid = threadIdx.x;
  int grp = tid >> 5, lane = tid & 31;
  int r = blockIdx.x * 8 + grp;
  size_t src = shifted ? map_row(r) : (size_t)r;
  float4 v = *(const float4*)(x + src * 128 + lane * 4);
  float s  = v.x + v.y + v.z + v.w;
  float ss = v.x*v.x + v.y*v.y + v.z*v.z + v.w*v.w;
  #pragma unroll
  for (int o = 16; o; o >>= 1) {
    s  += __shfl_xor(s,  o, 32);
    ss += __shfl_xor(ss, o, 32);
  }
  float mu   = s * (1.f/128.f);
  float var  = ss * (1.f/128.f) - mu * mu;
  float rstd = rsqrtf(var + EPSL);
  float4 gv = *(const float4*)(g + lane*4);
  float4 bv = *(const float4*)(b + lane*4);
  float4 o4;
  o4.x = (v.x-mu)*rstd*gv.x + bv.x;
  o4.y = (v.y-mu)*rstd*gv.y + bv.y;
  o4.z = (v.z-mu)*rstd*gv.z + bv.z;
  o4.w = (v.w-mu)*rstd*gv.w + bv.w;
  *(float4*)(out + (size_t)r*128 + lane*4) = o4;
}

// fp32 GEMM: C[M,N] = A[M,K] @ B[K,N]. 64x64 tile, 256 thr, 4x4 per thread.
// mode 0: Cout[r*ldc+c] = acc + bias (act: exact gelu)
// mode 1: dst=map_row(r); Cout[dst*128+c] = Xres[dst*128+c] + acc + bias (proj scatter+residual)
// mode 2: Cout[r*ldc+c] += acc + bias (fc2 accumulate)
__global__ __launch_bounds__(256) void k_gemm(
    const float* __restrict__ A, int lda,
    const float* __restrict__ Bw, int ldb,
    const float* __restrict__ bias,
    float* __restrict__ Cout, int ldc,
    const float* __restrict__ Xres,
    int K, int mode, int act)
{
  __shared__ float As[128][65];   // [k][row], padded: conflict-light transposed store
  __shared__ float Bs[128][64];   // [k][col]
  int tid = threadIdx.x;
  int tx = tid & 15, ty = tid >> 4;
  int row0 = blockIdx.y * 64, col0 = blockIdx.x * 64;
  float acc[4][4] = {};
  for (int k0 = 0; k0 < K; k0 += 128) {
    #pragma unroll
    for (int i = 0; i < 8; ++i) {
      int fidx = tid + i * 256;
      int rr = fidx >> 5, ac4 = fidx & 31;           // A: 32 float4 per row
      float4 av = *(const float4*)(A + (size_t)(row0 + rr) * lda + k0 + ac4 * 4);
      As[ac4*4+0][rr] = av.x;
      As[ac4*4+1][rr] = av.y;
      As[ac4*4+2][rr] = av.z;
      As[ac4*4+3][rr] = av.w;
      int kk = fidx >> 4, bc4 = fidx & 15;           // B: 16 float4 per row
      *(float4*)(&Bs[kk][bc4*4]) =
          *(const float4*)(Bw + (size_t)(k0 + kk) * ldb + col0 + bc4 * 4);
    }
    __syncthreads();
    #pragma unroll 8
    for (int kk = 0; kk < 128; ++kk) {
      float a0 = As[kk][ty*4+0];
      float a1 = As[kk][ty*4+1];
      float a2 = As[kk][ty*4+2];
      float a3 = As[kk][ty*4+3];
      float4 bv4 = *(const float4*)(&Bs[kk][tx*4]);
      acc[0][0] += a0*bv4.x; acc[0][1] += a0*bv4.y; acc[0][2] += a0*bv4.z; acc[0][3] += a0*bv4.w;
      acc[1][0] += a1*bv4.x; acc[1][1] += a1*bv4.y; acc[1][2] += a1*bv4.z; acc[1][3] += a1*bv4.w;
      acc[2][0] += a2*bv4.x; acc[2][1] += a2*bv4.y; acc[2][2] += a2*bv4.z; acc[2][3] += a2*bv4.w;
      acc[3][0] += a3*bv4.x; acc[3][1] += a3*bv4.y; acc[3][2] += a3*bv4.z; acc[3][3] += a3*bv4.w;
    }
    __syncthreads();
  }
  float b0 = 0.f, b1 = 0.f, b2 = 0.f, b3 = 0.f;
  if (bias) {
    b0 = bias[col0+tx*4+0]; b1 = bias[col0+tx*4+1];
    b2 = bias[col0+tx*4+2]; b3 = bias[col0+tx*4+3];
  }
  #pragma unroll
  for (int i = 0; i < 4; ++i) {
    int r = row0 + ty*4 + i;
    float4 v4;
    v4.x = acc[i][0] + b0; v4.y = acc[i][1] + b1;
    v4.z = acc[i][2] + b2; v4.w = acc[i][3] + b3;
    if (act) {   // exact gelu: 0.5*x*(1+erf(x/sqrt(2)))
      v4.x = 0.5f*v4.x*(1.f+erff(v4.x*0.7071067811865476f));
      v4.y = 0.5f*v4.y*(1.f+erff(v4.y*0.7071067811865476f));
      v4.z = 0.5f*v4.z*(1.f+erff(v4.z*0.7071067811865476f));
      v4.w = 0.5f*v4.w*(1.f+erff(v4.w*0.7071067811865476f));
    }
    if (mode == 0) {
      *(float4*)(Cout + (size_t)r*ldc + col0 + tx*4) = v4;
    } else if (mode == 1) {
      size_t dst = map_row(r);
      float4 xv = *(const float4*)(Xres + dst*128 + col0 + tx*4);
      v4.x += xv.x; v4.y += xv.y; v4.z += xv.z; v4.w += xv.w;
      *(float4*)(Cout + dst*128 + col0 + tx*4) = v4;
    } else {
      float4 cv = *(const float4*)(Cout + (size_t)r*ldc + col0 + tx*4);
      v4.x += cv.x; v4.y += cv.y; v4.z += cv.z; v4.w += cv.w;
      *(float4*)(Cout + (size_t)r*ldc + col0 + tx*4) = v4;
    }
  }
}

// Attention: one block per (window, head). q/k/v + scores in LDS.
__global__ __launch_bounds__(256) void k_attn(
    const float* __restrict__ qkv,     // (ROWS, 384) = [3][4 heads][32]
    const float* __restrict__ mask,    // (512, 98, 98)
    const int*   __restrict__ relidx,  // (98, 98)
    const float* __restrict__ rtab,    // (507, 4)
    float* __restrict__ o_part)        // (ROWS, 128)
{
  __shared__ float qs[100][36];
  __shared__ float ks[100][36];
  __shared__ float vs[100][36];
  __shared__ float Ss[98][98];
  int tid  = threadIdx.x;
  int head = blockIdx.x & 3;
  int win  = blockIdx.x >> 2;
  int widx = win & 511;
  const float* base = qkv + (size_t)win * 98 * 384 + head * 32;
  for (int idx = tid; idx < 100 * 32; idx += 256) {
    int n = idx >> 5, d = idx & 31;
    float q = 0.f, k = 0.f, v = 0.f;
    if (n < 98) {
      q = base[n*384 + d] * SCALE_Q;
      k = base[n*384 + 128 + d];
      v = base[n*384 + 256 + d];
    }
    qs[n][d] = q; ks[n][d] = k; vs[n][d] = v;
  }
  __syncthreads();
  // S = q k^T + rel_bias + mask ; 2n x 4m register tiles
  const float* mrow = mask + (size_t)widx * 9604;
  for (int t = tid; t < 49 * 25; t += 256) {
    int n0 = (t / 25) * 2;
    int m0 = (t % 25) * 4;
    float a[2][4] = {};
    #pragma unroll
    for (int d4 = 0; d4 < 8; ++d4) {
      float4 q0 = *(const float4*)&qs[n0  ][d4*4];
      float4 q1 = *(const float4*)&qs[n0+1][d4*4];
      #pragma unroll
      for (int j = 0; j < 4; ++j) {
        float4 kv = *(const float4*)&ks[m0+j][d4*4];
        a[0][j] += q0.x*kv.x + q0.y*kv.y + q0.z*kv.z + q0.w*kv.w;
        a[1][j] += q1.x*kv.x + q1.y*kv.y + q1.z*kv.z + q1.w*kv.w;
      }
    }
    #pragma unroll
    for (int i = 0; i < 2; ++i)
      #pragma unroll
      for (int j = 0; j < 4; ++j) {
        int n = n0 + i, m = m0 + j;
        if (m < 98) {
          int e = n*98 + m;
          Ss[n][m] = a[i][j] + rtab[relidx[e]*4 + head] + mrow[e];
        }
      }
  }
  __syncthreads();
  // softmax per row: wave per row (rows strided by 4 waves)
  int wv = tid >> 6, lane = tid & 63;
  for (int n = wv; n < 98; n += 4) {
    float v0 = Ss[n][lane];
    float v1 = (lane < 34) ? Ss[n][lane + 64] : -1e30f;
    float mx = fmaxf(v0, v1);
    #pragma unroll
    for (int o = 32; o; o >>= 1) mx = fmaxf(mx, __shfl_xor(mx, o));
    float e0 = __expf(v0 - mx);
    float e1 = (lane < 34) ? __expf(v1 - mx) : 0.f;
    float sum = e0 + e1;
    #pragma unroll
    for (int o = 32; o; o >>= 1) sum += __shfl_xor(sum, o);
    float inv = 1.f / sum;
    Ss[n][lane] = e0 * inv;
    if (lane < 34) Ss[n][lane + 64] = e1 * inv;
  }
  __syncthreads();
  // O = P V ; 2n x 4d register tiles
  float* orow = o_part + (size_t)win * 98 * 128 + head * 32;
  for (int t = tid; t < 49 * 8; t += 256) {
    int n0 = (t >> 3) * 2;
    int d0 = (t & 7) * 4;
    float a[2][4] = {};
    for (int m = 0; m < 98; ++m) {
      float4 vv = *(const float4*)&vs[m][d0];
      float p0 = Ss[n0][m], p1 = Ss[n0+1][m];
      a[0][0] += p0*vv.x; a[0][1] += p0*vv.y; a[0][2] += p0*vv.z; a[0][3] += p0*vv.w;
      a[1][0] += p1*vv.x; a[1][1] += p1*vv.y; a[1][2] += p1*vv.z; a[1][3] += p1*vv.w;
    }
    *(float4*)(orow + (size_t)(n0  )*128 + d0) = make_float4(a[0][0],a[0][1],a[0][2],a[0][3]);
    *(float4*)(orow + (size_t)(n0+1)*128 + d0) = make_float4(a[1][0],a[1][1],a[1][2],a[1][3]);
  }
}

extern "C" void kernel_launch(void* const* d_in, const int* in_sizes, int n_in,
                              void* d_out, int out_size, void* d_ws, size_t ws_size,
                              hipStream_t stream)
{
  const float* x         = (const float*)d_in[0];
  const float* attn_mask = (const float*)d_in[1];
  const int*   rel_index = (const int*)  d_in[2];
  const float* n1g       = (const float*)d_in[3];
  const float* n1b       = (const float*)d_in[4];
  const float* qkv_w     = (const float*)d_in[5];
  const float* qkv_b     = (const float*)d_in[6];
  const float* rtab      = (const float*)d_in[7];
  const float* proj_w    = (const float*)d_in[8];
  const float* proj_b    = (const float*)d_in[9];
  const float* n2g       = (const float*)d_in[10];
  const float* n2b       = (const float*)d_in[11];
  const float* fc1_w     = (const float*)d_in[12];
  const float* fc1_b     = (const float*)d_in[13];
  const float* fc2_w     = (const float*)d_in[14];
  const float* fc2_b     = (const float*)d_in[15];
  float* out = (float*)d_out;

  // ws layout: bufA = ROWS*384 (qkv, later fc1 chunk) ; bufB = ROWS*128
  float* bufA = (float*)d_ws;
  float* bufB = bufA + (size_t)ROWS * 384;

  // 1. LN1 + shift + window partition  -> bufB (h_part)
  k_ln<<<ROWS/8, 256, 0, stream>>>(x, n1g, n1b, bufB, 1);

  // 2. qkv = h_part @ qkv_w + qkv_b  -> bufA
  k_gemm<<<dim3(6, ROWS/64), 256, 0, stream>>>(
      bufB, 128, qkv_w, 384, qkv_b, bufA, 384, nullptr, 128, 0, 0);

  // 3. windowed attention -> bufB (o_part, heads concatenated)
  k_attn<<<4096, 256, 0, stream>>>(bufA, attn_mask, rel_index, rtab, bufB);

  // 4. proj + window-reverse/unshift scatter + residual -> out = x1
  k_gemm<<<dim3(2, ROWS/64), 256, 0, stream>>>(
      bufB, 128, proj_w, 128, proj_b, out, 128, x, 128, 1, 0);

  // 5. LN2(x1) -> bufB (h2)
  k_ln<<<ROWS/8, 256, 0, stream>>>(out, n2g, n2b, bufB, 0);

  // 6/7. MLP in 4 column chunks of 128: fc1+gelu -> bufA chunk; fc2 accumulates into out
  for (int j = 0; j < 4; ++j) {
    k_gemm<<<dim3(2, ROWS/64), 256, 0, stream>>>(
        bufB, 128, fc1_w + j*128, 512, fc1_b + j*128, bufA, 128, nullptr, 128, 0, 1);
    k_gemm<<<dim3(2, ROWS/64), 256, 0, stream>>>(
        bufA, 128, fc2_w + (size_t)j*128*128, 128, (j == 0) ? fc2_b : nullptr,
        out, 128, nullptr, 128, 2, 0);
  }
}

// Round 2
// 719.563 us; speedup vs baseline: 1.5329x; 1.5329x over previous
//
#include <hip/hip_runtime.h>
#include <math.h>

#define ROWS 100352        // B * NW * N = 2*512*98
#define EPSL 1e-5f
#define SCALE_Q 0.17677669529663687f   // 32^-0.5

typedef __attribute__((ext_vector_type(8))) short bf16x8;
typedef __attribute__((ext_vector_type(4))) float f32x4;

__device__ __forceinline__ unsigned short f2b(float f) {
  union { float f; unsigned int u; } a; a.f = f;
  unsigned int u = a.u;
  return (unsigned short)((u + 0x7FFF + ((u >> 16) & 1)) >> 16);  // RNE
}
__device__ __forceinline__ float b2f(unsigned short s) {
  union { unsigned int u; float f; } a; a.u = ((unsigned int)s) << 16;
  return a.f;
}

// partition-row -> x flat spatial index (applies shift)
__device__ __forceinline__ size_t map_row(int r) {
  int t = r;
  int tw = t % 7; t /= 7;
  int th = t % 7; t /= 7;
  int td = t & 1;  t >>= 1;
  int zw = t & 7;  t >>= 3;
  int zh = t & 7;  t >>= 3;
  int zd = t & 7;  int bb = t >> 3;
  int d = zd * 2 + td;
  int h = zh * 7 + th;
  int w = zw * 7 + tw;
  int sd = (d + 1) & 15;
  int sh = h + 3; if (sh >= 56) sh -= 56;
  int sw = w + 3; if (sw >= 56) sw -= 56;
  return ((size_t)((bb * 16 + sd) * 56 + sh)) * 56 + sw;
}

// transpose + fp32->bf16: W[K][N] -> Wt[N][K]
__global__ void k_prep(const float* __restrict__ W, unsigned short* __restrict__ Wt,
                       int K, int N) {
  int id = blockIdx.x * 256 + threadIdx.x;
  if (id >= K * N) return;
  int n = id / K, k = id - n * K;
  Wt[id] = f2b(W[(size_t)k * N + n]);
}

// LayerNorm over C=128, bf16 output. shifted=1: gather via map_row.
__global__ __launch_bounds__(256) void k_ln(
    const float* __restrict__ x, const float* __restrict__ g,
    const float* __restrict__ b, unsigned short* __restrict__ out, int shifted)
{
  int tid = threadIdx.x;
  int grp = tid >> 5, lane = tid & 31;
  int r = blockIdx.x * 8 + grp;
  size_t src = shifted ? map_row(r) : (size_t)r;
  float4 v = *(const float4*)(x + src * 128 + lane * 4);
  float s  = v.x + v.y + v.z + v.w;
  float ss = v.x*v.x + v.y*v.y + v.z*v.z + v.w*v.w;
  #pragma unroll
  for (int o = 16; o; o >>= 1) {
    s  += __shfl_xor(s,  o, 32);
    ss += __shfl_xor(ss, o, 32);
  }
  float mu   = s * (1.f/128.f);
  float var  = ss * (1.f/128.f) - mu * mu;
  float rstd = rsqrtf(var + EPSL);
  float4 gv = *(const float4*)(g + lane*4);
  float4 bv = *(const float4*)(b + lane*4);
  ushort4 o4;
  o4.x = f2b((v.x-mu)*rstd*gv.x + bv.x);
  o4.y = f2b((v.y-mu)*rstd*gv.y + bv.y);
  o4.z = f2b((v.z-mu)*rstd*gv.z + bv.z);
  o4.w = f2b((v.w-mu)*rstd*gv.w + bv.w);
  *(ushort4*)(out + (size_t)r*128 + lane*4) = o4;
}

// bf16 MFMA GEMM: C[M,N] = A[M,K] @ Bt[N,K]^T. 128x128 tile, 4 waves (2x2),
// each wave 64x64 = 4x4 fragments of 16x16x32.
// mode 0: Cb[r*ldc+c] = acc+bias (bf16 out; act=gelu)
// mode 1: dst=map_row(r); Cf[dst*128+c] = Xres[dst*128+c]+acc+bias (fp32)
// mode 2: Cf[r*128+c] += acc+bias (fp32 accumulate)
__global__ __launch_bounds__(256) void k_gemm_mfma(
    const unsigned short* __restrict__ A, int lda,
    const unsigned short* __restrict__ Bt,
    const float* __restrict__ bias,
    unsigned short* __restrict__ Cb, int ldc,
    float* __restrict__ Cf,
    const float* __restrict__ Xres,
    int K, int mode, int act)
{
  __shared__ unsigned short As[128 * 136];
  __shared__ unsigned short Bs[128 * 136];
  int tid = threadIdx.x;
  int row0 = blockIdx.y * 128, col0 = blockIdx.x * 128;
  int l = tid & 63, w = tid >> 6;
  int wr = (w >> 1) * 64, wc = (w & 1) * 64;
  int fr = l & 15, fk = (l >> 4) * 8;
  f32x4 acc[4][4] = {};
  for (int k0 = 0; k0 < K; k0 += 128) {
    #pragma unroll
    for (int i = 0; i < 8; ++i) {
      int chunk = i * 256 + tid;
      int rr = chunk >> 4, off = (chunk & 15) * 8;
      *(uint4*)&As[rr*136 + off] = *(const uint4*)(A  + (size_t)(row0+rr)*lda + k0 + off);
      *(uint4*)&Bs[rr*136 + off] = *(const uint4*)(Bt + (size_t)(col0+rr)*K   + k0 + off);
    }
    __syncthreads();
    #pragma unroll
    for (int ks = 0; ks < 128; ks += 32) {
      bf16x8 af[4], bv[4];
      #pragma unroll
      for (int m = 0; m < 4; ++m)
        af[m] = *(bf16x8*)&As[(wr + m*16 + fr)*136 + ks + fk];
      #pragma unroll
      for (int n = 0; n < 4; ++n)
        bv[n] = *(bf16x8*)&Bs[(wc + n*16 + fr)*136 + ks + fk];
      #pragma unroll
      for (int m = 0; m < 4; ++m)
        #pragma unroll
        for (int n = 0; n < 4; ++n)
          acc[m][n] = __builtin_amdgcn_mfma_f32_16x16x32_bf16(af[m], bv[n], acc[m][n], 0, 0, 0);
    }
    __syncthreads();
  }
  #pragma unroll
  for (int m = 0; m < 4; ++m) {
    #pragma unroll
    for (int r = 0; r < 4; ++r) {
      int grow = row0 + wr + m*16 + (l >> 4)*4 + r;
      size_t dst = 0;
      if (mode == 1) dst = map_row(grow);
      #pragma unroll
      for (int n = 0; n < 4; ++n) {
        int col = col0 + wc + n*16 + fr;
        float v = acc[m][n][r] + (bias ? bias[col] : 0.f);
        if (act) v = 0.5f*v*(1.f + erff(v*0.7071067811865476f));
        if (mode == 0) {
          Cb[(size_t)grow*ldc + col] = f2b(v);
        } else if (mode == 1) {
          Cf[dst*128 + col] = v + Xres[dst*128 + col];
        } else {
          Cf[(size_t)grow*128 + col] += v;
        }
      }
    }
  }
}

// Attention: one block per (window, head). fp32 compute, bf16 in/out.
__global__ __launch_bounds__(256) void k_attn(
    const unsigned short* __restrict__ qkv,   // (ROWS, 384) bf16
    const float* __restrict__ mask,           // (512, 98, 98)
    const int*   __restrict__ relidx,         // (98, 98)
    const float* __restrict__ rtab,           // (507, 4)
    unsigned short* __restrict__ o_part)      // (ROWS, 128) bf16
{
  __shared__ float qs[100][36];
  __shared__ float ks[100][36];
  __shared__ float vs[100][36];
  __shared__ float Ss[98][98];
  int tid  = threadIdx.x;
  int head = blockIdx.x & 3;
  int win  = blockIdx.x >> 2;
  int widx = win & 511;
  const unsigned short* base = qkv + (size_t)win * 98 * 384 + head * 32;
  for (int idx = tid; idx < 100 * 32; idx += 256) {
    int n = idx >> 5, d = idx & 31;
    float q = 0.f, k = 0.f, v = 0.f;
    if (n < 98) {
      q = b2f(base[n*384 + d]) * SCALE_Q;
      k = b2f(base[n*384 + 128 + d]);
      v = b2f(base[n*384 + 256 + d]);
    }
    qs[n][d] = q; ks[n][d] = k; vs[n][d] = v;
  }
  __syncthreads();
  const float* mrow = mask + (size_t)widx * 9604;
  for (int t = tid; t < 49 * 25; t += 256) {
    int n0 = (t / 25) * 2;
    int m0 = (t % 25) * 4;
    float a[2][4] = {};
    #pragma unroll
    for (int d4 = 0; d4 < 8; ++d4) {
      float4 q0 = *(const float4*)&qs[n0  ][d4*4];
      float4 q1 = *(const float4*)&qs[n0+1][d4*4];
      #pragma unroll
      for (int j = 0; j < 4; ++j) {
        float4 kv = *(const float4*)&ks[m0+j][d4*4];
        a[0][j] += q0.x*kv.x + q0.y*kv.y + q0.z*kv.z + q0.w*kv.w;
        a[1][j] += q1.x*kv.x + q1.y*kv.y + q1.z*kv.z + q1.w*kv.w;
      }
    }
    #pragma unroll
    for (int i = 0; i < 2; ++i)
      #pragma unroll
      for (int j = 0; j < 4; ++j) {
        int n = n0 + i, m = m0 + j;
        if (m < 98) {
          int e = n*98 + m;
          Ss[n][m] = a[i][j] + rtab[relidx[e]*4 + head] + mrow[e];
        }
      }
  }
  __syncthreads();
  int wv = tid >> 6, lane = tid & 63;
  for (int n = wv; n < 98; n += 4) {
    float v0 = Ss[n][lane];
    float v1 = (lane < 34) ? Ss[n][lane + 64] : -1e30f;
    float mx = fmaxf(v0, v1);
    #pragma unroll
    for (int o = 32; o; o >>= 1) mx = fmaxf(mx, __shfl_xor(mx, o));
    float e0 = __expf(v0 - mx);
    float e1 = (lane < 34) ? __expf(v1 - mx) : 0.f;
    float sum = e0 + e1;
    #pragma unroll
    for (int o = 32; o; o >>= 1) sum += __shfl_xor(sum, o);
    float inv = 1.f / sum;
    Ss[n][lane] = e0 * inv;
    if (lane < 34) Ss[n][lane + 64] = e1 * inv;
  }
  __syncthreads();
  unsigned short* orow = o_part + (size_t)win * 98 * 128 + head * 32;
  for (int t = tid; t < 49 * 8; t += 256) {
    int n0 = (t >> 3) * 2;
    int d0 = (t & 7) * 4;
    float a[2][4] = {};
    for (int m = 0; m < 98; ++m) {
      float4 vv = *(const float4*)&vs[m][d0];
      float p0 = Ss[n0][m], p1 = Ss[n0+1][m];
      a[0][0] += p0*vv.x; a[0][1] += p0*vv.y; a[0][2] += p0*vv.z; a[0][3] += p0*vv.w;
      a[1][0] += p1*vv.x; a[1][1] += p1*vv.y; a[1][2] += p1*vv.z; a[1][3] += p1*vv.w;
    }
    ushort4 u0, u1;
    u0.x = f2b(a[0][0]); u0.y = f2b(a[0][1]); u0.z = f2b(a[0][2]); u0.w = f2b(a[0][3]);
    u1.x = f2b(a[1][0]); u1.y = f2b(a[1][1]); u1.z = f2b(a[1][2]); u1.w = f2b(a[1][3]);
    *(ushort4*)(orow + (size_t)(n0  )*128 + d0) = u0;
    *(ushort4*)(orow + (size_t)(n0+1)*128 + d0) = u1;
  }
}

extern "C" void kernel_launch(void* const* d_in, const int* in_sizes, int n_in,
                              void* d_out, int out_size, void* d_ws, size_t ws_size,
                              hipStream_t stream)
{
  const float* x         = (const float*)d_in[0];
  const float* attn_mask = (const float*)d_in[1];
  const int*   rel_index = (const int*)  d_in[2];
  const float* n1g       = (const float*)d_in[3];
  const float* n1b       = (const float*)d_in[4];
  const float* qkv_w     = (const float*)d_in[5];
  const float* qkv_b     = (const float*)d_in[6];
  const float* rtab      = (const float*)d_in[7];
  const float* proj_w    = (const float*)d_in[8];
  const float* proj_b    = (const float*)d_in[9];
  const float* n2g       = (const float*)d_in[10];
  const float* n2b       = (const float*)d_in[11];
  const float* fc1_w     = (const float*)d_in[12];
  const float* fc1_b     = (const float*)d_in[13];
  const float* fc2_w     = (const float*)d_in[14];
  const float* fc2_b     = (const float*)d_in[15];
  float* out = (float*)d_out;

  // ws layout (all bf16/ushort): buf0 ROWS*512, buf1 ROWS*128, then weights
  unsigned short* buf0  = (unsigned short*)d_ws;
  unsigned short* buf1  = buf0 + (size_t)ROWS * 512;
  unsigned short* qkvT  = buf1 + (size_t)ROWS * 128;
  unsigned short* projT = qkvT + 384 * 128;
  unsigned short* fc1T  = projT + 128 * 128;
  unsigned short* fc2T  = fc1T + 512 * 128;

  // 0. weight transpose+convert (W[K][N] -> Wt[N][K] bf16)
  k_prep<<<(384*128 + 255)/256, 256, 0, stream>>>(qkv_w, qkvT, 128, 384);
  k_prep<<<(128*128 + 255)/256, 256, 0, stream>>>(proj_w, projT, 128, 128);
  k_prep<<<(512*128 + 255)/256, 256, 0, stream>>>(fc1_w, fc1T, 128, 512);
  k_prep<<<(512*128 + 255)/256, 256, 0, stream>>>(fc2_w, fc2T, 512, 128);

  // 1. LN1 + shift + window partition -> buf1 (bf16)
  k_ln<<<ROWS/8, 256, 0, stream>>>(x, n1g, n1b, buf1, 1);

  // 2. qkv = h @ qkv_w + b -> buf0 (bf16, ld 384)
  k_gemm_mfma<<<dim3(3, ROWS/128), 256, 0, stream>>>(
      buf1, 128, qkvT, qkv_b, buf0, 384, nullptr, nullptr, 128, 0, 0);

  // 3. windowed attention -> buf1 (bf16)
  k_attn<<<4096, 256, 0, stream>>>(buf0, attn_mask, rel_index, rtab, buf1);

  // 4. proj + reverse/unshift scatter + residual -> out (fp32)
  k_gemm_mfma<<<dim3(1, ROWS/128), 256, 0, stream>>>(
      buf1, 128, projT, proj_b, nullptr, 128, out, x, 128, 1, 0);

  // 5. LN2 -> buf1 (bf16)
  k_ln<<<ROWS/8, 256, 0, stream>>>(out, n2g, n2b, buf1, 0);

  // 6. fc1 + exact gelu -> buf0 (bf16, ld 512)
  k_gemm_mfma<<<dim3(4, ROWS/128), 256, 0, stream>>>(
      buf1, 128, fc1T, fc1_b, buf0, 512, nullptr, nullptr, 128, 0, 1);

  // 7. fc2, accumulate into out (residual)
  k_gemm_mfma<<<dim3(1, ROWS/128), 256, 0, stream>>>(
      buf0, 512, fc2T, fc2_b, nullptr, 128, out, nullptr, 512, 2, 0);
}

// Round 3
// 520.693 us; speedup vs baseline: 2.1183x; 1.3819x over previous
//
#include <hip/hip_runtime.h>
#include <math.h>

#define ROWS 100352        // B * NW * N = 2*512*98
#define EPSL 1e-5f
#define SCALE_Q 0.17677669529663687f   // 32^-0.5

typedef __attribute__((ext_vector_type(8))) short bf16x8;
typedef __attribute__((ext_vector_type(4))) float f32x4;

__device__ __forceinline__ unsigned short f2b(float f) {
  union { float f; unsigned int u; } a; a.f = f;
  unsigned int u = a.u;
  return (unsigned short)((u + 0x7FFF + ((u >> 16) & 1)) >> 16);  // RNE
}
__device__ __forceinline__ float b2f(unsigned short s) {
  union { unsigned int u; float f; } a; a.u = ((unsigned int)s) << 16;
  return a.f;
}

// partition-row -> x flat spatial index (applies shift)
__device__ __forceinline__ size_t map_row(int r) {
  int t = r;
  int tw = t % 7; t /= 7;
  int th = t % 7; t /= 7;
  int td = t & 1;  t >>= 1;
  int zw = t & 7;  t >>= 3;
  int zh = t & 7;  t >>= 3;
  int zd = t & 7;  int bb = t >> 3;
  int d = zd * 2 + td;
  int h = zh * 7 + th;
  int w = zw * 7 + tw;
  int sd = (d + 1) & 15;
  int sh = h + 3; if (sh >= 56) sh -= 56;
  int sw = w + 3; if (sw >= 56) sw -= 56;
  return ((size_t)((bb * 16 + sd) * 56 + sh)) * 56 + sw;
}

// transpose + fp32->bf16: W[K][N] -> Wt[N][K]
__global__ void k_prep(const float* __restrict__ W, unsigned short* __restrict__ Wt,
                       int K, int N) {
  int id = blockIdx.x * 256 + threadIdx.x;
  if (id >= K * N) return;
  int n = id / K, k = id - n * K;
  Wt[id] = f2b(W[(size_t)k * N + n]);
}

// biasTab[h][n*98+m] = rtab[relidx[n*98+m]*4 + h]
__global__ void k_prep_bias(const int* __restrict__ relidx,
                            const float* __restrict__ rtab,
                            float* __restrict__ biasTab) {
  int id = blockIdx.x * 256 + threadIdx.x;
  if (id >= 9604) return;
  int ri = relidx[id];
  #pragma unroll
  for (int h = 0; h < 4; ++h)
    biasTab[h * 9604 + id] = rtab[ri * 4 + h];
}

// LayerNorm over C=128, bf16 output. shifted=1: gather via map_row.
__global__ __launch_bounds__(256) void k_ln(
    const float* __restrict__ x, const float* __restrict__ g,
    const float* __restrict__ b, unsigned short* __restrict__ out, int shifted)
{
  int tid = threadIdx.x;
  int grp = tid >> 5, lane = tid & 31;
  int r = blockIdx.x * 8 + grp;
  size_t src = shifted ? map_row(r) : (size_t)r;
  float4 v = *(const float4*)(x + src * 128 + lane * 4);
  float s  = v.x + v.y + v.z + v.w;
  float ss = v.x*v.x + v.y*v.y + v.z*v.z + v.w*v.w;
  #pragma unroll
  for (int o = 16; o; o >>= 1) {
    s  += __shfl_xor(s,  o, 32);
    ss += __shfl_xor(ss, o, 32);
  }
  float mu   = s * (1.f/128.f);
  float var  = ss * (1.f/128.f) - mu * mu;
  float rstd = rsqrtf(var + EPSL);
  float4 gv = *(const float4*)(g + lane*4);
  float4 bv = *(const float4*)(b + lane*4);
  ushort4 o4;
  o4.x = f2b((v.x-mu)*rstd*gv.x + bv.x);
  o4.y = f2b((v.y-mu)*rstd*gv.y + bv.y);
  o4.z = f2b((v.z-mu)*rstd*gv.z + bv.z);
  o4.w = f2b((v.w-mu)*rstd*gv.w + bv.w);
  *(ushort4*)(out + (size_t)r*128 + lane*4) = o4;
}

// bf16 MFMA GEMM: C[M,N] = A[M,K] @ Bt[N,K]^T. 128x128 tile, 4 waves (2x2).
__global__ __launch_bounds__(256) void k_gemm_mfma(
    const unsigned short* __restrict__ A, int lda,
    const unsigned short* __restrict__ Bt,
    const float* __restrict__ bias,
    unsigned short* __restrict__ Cb, int ldc,
    float* __restrict__ Cf,
    const float* __restrict__ Xres,
    int K, int mode, int act)
{
  __shared__ unsigned short As[128 * 136];
  __shared__ unsigned short Bs[128 * 136];
  int tid = threadIdx.x;
  int row0 = blockIdx.y * 128, col0 = blockIdx.x * 128;
  int l = tid & 63, w = tid >> 6;
  int wr = (w >> 1) * 64, wc = (w & 1) * 64;
  int fr = l & 15, fk = (l >> 4) * 8;
  f32x4 acc[4][4] = {};
  for (int k0 = 0; k0 < K; k0 += 128) {
    #pragma unroll
    for (int i = 0; i < 8; ++i) {
      int chunk = i * 256 + tid;
      int rr = chunk >> 4, off = (chunk & 15) * 8;
      *(uint4*)&As[rr*136 + off] = *(const uint4*)(A  + (size_t)(row0+rr)*lda + k0 + off);
      *(uint4*)&Bs[rr*136 + off] = *(const uint4*)(Bt + (size_t)(col0+rr)*K   + k0 + off);
    }
    __syncthreads();
    #pragma unroll
    for (int ks = 0; ks < 128; ks += 32) {
      bf16x8 af[4], bv[4];
      #pragma unroll
      for (int m = 0; m < 4; ++m)
        af[m] = *(bf16x8*)&As[(wr + m*16 + fr)*136 + ks + fk];
      #pragma unroll
      for (int n = 0; n < 4; ++n)
        bv[n] = *(bf16x8*)&Bs[(wc + n*16 + fr)*136 + ks + fk];
      #pragma unroll
      for (int m = 0; m < 4; ++m)
        #pragma unroll
        for (int n = 0; n < 4; ++n)
          acc[m][n] = __builtin_amdgcn_mfma_f32_16x16x32_bf16(af[m], bv[n], acc[m][n], 0, 0, 0);
    }
    __syncthreads();
  }
  #pragma unroll
  for (int m = 0; m < 4; ++m) {
    #pragma unroll
    for (int r = 0; r < 4; ++r) {
      int grow = row0 + wr + m*16 + (l >> 4)*4 + r;
      size_t dst = 0;
      if (mode == 1) dst = map_row(grow);
      #pragma unroll
      for (int n = 0; n < 4; ++n) {
        int col = col0 + wc + n*16 + fr;
        float v = acc[m][n][r] + (bias ? bias[col] : 0.f);
        if (act) v = 0.5f*v*(1.f + erff(v*0.7071067811865476f));
        if (mode == 0) {
          Cb[(size_t)grow*ldc + col] = f2b(v);
        } else if (mode == 1) {
          Cf[dst*128 + col] = v + Xres[dst*128 + col];
        } else {
          Cf[(size_t)grow*128 + col] += v;
        }
      }
    }
  }
}

// MFMA attention: one block per (window, head), 4 waves, wave w owns rows 32w..32w+31.
// M (queries) padded to 128, N (keys) padded to 112, head_dim 32.
__global__ __launch_bounds__(256) void k_attn_mfma(
    const unsigned short* __restrict__ qkv,     // (ROWS, 384) bf16
    const float* __restrict__ biasTab,          // (4, 98, 98)
    unsigned short* __restrict__ o_part)        // (ROWS, 128) bf16
{
  __shared__ unsigned short Kb[112 * 40];   // [key row][d] pad 40
  __shared__ unsigned short Vt[32 * 136];   // [d][key row] pad 136
  __shared__ unsigned short Pb[128 * 136];  // [query row][key] pad 136
  __shared__ unsigned char cls[112];
  int tid  = threadIdx.x;
  int head = blockIdx.x & 3;
  int win  = blockIdx.x >> 2;
  int widx = win & 511;
  int zd = widx >> 6, zh = (widx >> 3) & 7, zw = widx & 7;
  int wmask = (zd == 7 ? 1 : 0) | (zh == 7 ? 2 : 0) | (zw == 7 ? 4 : 0);
  const unsigned short* base = qkv + (size_t)win * 98 * 384 + head * 32;

  // ---- stage K (rows 0..111, zero-padded) ----
  for (int it = tid; it < 112 * 4; it += 256) {
    int n = it >> 2, c = (it & 3) << 3;
    bf16x8 kv = {0,0,0,0,0,0,0,0};
    if (n < 98) kv = *(const bf16x8*)(base + n*384 + 128 + c);
    *(bf16x8*)&Kb[n*40 + c] = kv;
  }
  // ---- stage V transposed: Vt[d][m] ----
  for (int it = tid; it < 32 * 128; it += 256) {
    int d = it & 31, m = it >> 5;
    unsigned short v = 0;
    if (m < 98) v = base[m*384 + 256 + d];
    Vt[d*136 + m] = v;
  }
  // ---- zero Pb pad columns 112..127 ----
  for (int it = tid; it < 128 * 16; it += 256) {
    int n = it >> 4, c = 112 + (it & 15);
    Pb[n*136 + c] = 0;
  }
  // ---- token class bits: {td, th>=4, tw>=4} ----
  if (tid < 112) {
    int i = tid;
    cls[i] = (unsigned char)((i >= 49 ? 1 : 0) |
                             (((i % 49) >= 28) ? 2 : 0) |
                             (((i % 7) >= 4) ? 4 : 0));
  }
  __syncthreads();

  int l = tid & 63, w = tid >> 6;
  int fr = l & 15, g = l >> 4;
  int fk = g * 8;

  // ---- QK^T: 2 row tiles x 7 col tiles per wave ----
  bf16x8 aq[2];
  #pragma unroll
  for (int lt = 0; lt < 2; ++lt) {
    int row = (w*2 + lt)*16 + fr;
    bf16x8 q = {0,0,0,0,0,0,0,0};
    if (row < 98) q = *(const bf16x8*)(base + row*384 + fk);
    aq[lt] = q;
  }
  f32x4 S[2][7];
  #pragma unroll
  for (int ct = 0; ct < 7; ++ct) {
    bf16x8 b = *(bf16x8*)&Kb[(ct*16 + fr)*40 + fk];
    #pragma unroll
    for (int lt = 0; lt < 2; ++lt)
      S[lt][ct] = __builtin_amdgcn_mfma_f32_16x16x32_bf16(aq[lt], b, (f32x4){0.f,0.f,0.f,0.f}, 0, 0, 0);
  }

  // ---- scale + rel-bias + analytic shift mask ----
  const float* brow = biasTab + head * 9604;
  #pragma unroll
  for (int ct = 0; ct < 7; ++ct) {
    int m = ct*16 + fr;
    int cm = cls[m];
    #pragma unroll
    for (int lt = 0; lt < 2; ++lt) {
      #pragma unroll
      for (int r = 0; r < 4; ++r) {
        int n = w*32 + lt*16 + g*4 + r;
        float s = S[lt][ct][r] * SCALE_Q;
        if (m < 98) {
          if (n < 98) {
            s += brow[n*98 + m];
            if ((cls[n] ^ cm) & wmask) s -= 100.f;
          }
        } else {
          s = -1e30f;
        }
        S[lt][ct][r] = s;
      }
    }
  }

  // ---- softmax per row (row = (g, r); 16 lanes x 7 tiles hold the 112 cols) ----
  #pragma unroll
  for (int lt = 0; lt < 2; ++lt) {
    #pragma unroll
    for (int r = 0; r < 4; ++r) {
      float mx = -1e30f;
      #pragma unroll
      for (int ct = 0; ct < 7; ++ct) mx = fmaxf(mx, S[lt][ct][r]);
      #pragma unroll
      for (int o = 8; o; o >>= 1) mx = fmaxf(mx, __shfl_xor(mx, o));
      float e[7], sum = 0.f;
      #pragma unroll
      for (int ct = 0; ct < 7; ++ct) { e[ct] = __expf(S[lt][ct][r] - mx); sum += e[ct]; }
      #pragma unroll
      for (int o = 8; o; o >>= 1) sum += __shfl_xor(sum, o);
      float inv = 1.f / sum;
      #pragma unroll
      for (int ct = 0; ct < 7; ++ct) S[lt][ct][r] = e[ct] * inv;
    }
  }

  // ---- P -> LDS (bf16) ----
  #pragma unroll
  for (int lt = 0; lt < 2; ++lt)
    #pragma unroll
    for (int ct = 0; ct < 7; ++ct)
      #pragma unroll
      for (int r = 0; r < 4; ++r) {
        int n = w*32 + lt*16 + g*4 + r;
        int m = ct*16 + fr;
        Pb[n*136 + m] = f2b(S[lt][ct][r]);
      }
  __syncthreads();

  // ---- PV: O[128x32] ; per wave 2 row tiles x 2 col tiles, K=112 pad 128 ----
  f32x4 O[2][2] = {};
  #pragma unroll
  for (int ks = 0; ks < 4; ++ks) {
    bf16x8 ap[2], bv[2];
    #pragma unroll
    for (int lt = 0; lt < 2; ++lt)
      ap[lt] = *(bf16x8*)&Pb[((w*2 + lt)*16 + fr)*136 + ks*32 + fk];
    #pragma unroll
    for (int vt = 0; vt < 2; ++vt)
      bv[vt] = *(bf16x8*)&Vt[(vt*16 + fr)*136 + ks*32 + fk];
    #pragma unroll
    for (int lt = 0; lt < 2; ++lt)
      #pragma unroll
      for (int vt = 0; vt < 2; ++vt)
        O[lt][vt] = __builtin_amdgcn_mfma_f32_16x16x32_bf16(ap[lt], bv[vt], O[lt][vt], 0, 0, 0);
  }

  // ---- store O ----
  #pragma unroll
  for (int lt = 0; lt < 2; ++lt)
    #pragma unroll
    for (int r = 0; r < 4; ++r) {
      int n = w*32 + lt*16 + g*4 + r;
      if (n < 98) {
        unsigned short* orow = o_part + ((size_t)win*98 + n)*128 + head*32;
        #pragma unroll
        for (int vt = 0; vt < 2; ++vt)
          orow[vt*16 + fr] = f2b(O[lt][vt][r]);
      }
    }
}

extern "C" void kernel_launch(void* const* d_in, const int* in_sizes, int n_in,
                              void* d_out, int out_size, void* d_ws, size_t ws_size,
                              hipStream_t stream)
{
  const float* x         = (const float*)d_in[0];
  const int*   rel_index = (const int*)  d_in[2];
  const float* n1g       = (const float*)d_in[3];
  const float* n1b       = (const float*)d_in[4];
  const float* qkv_w     = (const float*)d_in[5];
  const float* qkv_b     = (const float*)d_in[6];
  const float* rtab      = (const float*)d_in[7];
  const float* proj_w    = (const float*)d_in[8];
  const float* proj_b    = (const float*)d_in[9];
  const float* n2g       = (const float*)d_in[10];
  const float* n2b       = (const float*)d_in[11];
  const float* fc1_w     = (const float*)d_in[12];
  const float* fc1_b     = (const float*)d_in[13];
  const float* fc2_w     = (const float*)d_in[14];
  const float* fc2_b     = (const float*)d_in[15];
  float* out = (float*)d_out;

  // ws layout: buf0 ROWS*512 u16, buf1 ROWS*128 u16, weights (bf16), biasTab (f32)
  unsigned short* buf0  = (unsigned short*)d_ws;
  unsigned short* buf1  = buf0 + (size_t)ROWS * 512;
  unsigned short* qkvT  = buf1 + (size_t)ROWS * 128;
  unsigned short* projT = qkvT + 384 * 128;
  unsigned short* fc1T  = projT + 128 * 128;
  unsigned short* fc2T  = fc1T + 512 * 128;
  float* biasTab        = (float*)(fc2T + 128 * 512);

  // 0. weight transpose+convert ; bias table
  k_prep<<<(384*128 + 255)/256, 256, 0, stream>>>(qkv_w, qkvT, 128, 384);
  k_prep<<<(128*128 + 255)/256, 256, 0, stream>>>(proj_w, projT, 128, 128);
  k_prep<<<(512*128 + 255)/256, 256, 0, stream>>>(fc1_w, fc1T, 128, 512);
  k_prep<<<(512*128 + 255)/256, 256, 0, stream>>>(fc2_w, fc2T, 512, 128);
  k_prep_bias<<<(9604 + 255)/256, 256, 0, stream>>>(rel_index, rtab, biasTab);

  // 1. LN1 + shift + window partition -> buf1 (bf16)
  k_ln<<<ROWS/8, 256, 0, stream>>>(x, n1g, n1b, buf1, 1);

  // 2. qkv = h @ qkv_w + b -> buf0 (bf16, ld 384)
  k_gemm_mfma<<<dim3(3, ROWS/128), 256, 0, stream>>>(
      buf1, 128, qkvT, qkv_b, buf0, 384, nullptr, nullptr, 128, 0, 0);

  // 3. MFMA windowed attention -> buf1 (bf16)
  k_attn_mfma<<<4096, 256, 0, stream>>>(buf0, biasTab, buf1);

  // 4. proj + reverse/unshift scatter + residual -> out (fp32)
  k_gemm_mfma<<<dim3(1, ROWS/128), 256, 0, stream>>>(
      buf1, 128, projT, proj_b, nullptr, 128, out, x, 128, 1, 0);

  // 5. LN2 -> buf1 (bf16)
  k_ln<<<ROWS/8, 256, 0, stream>>>(out, n2g, n2b, buf1, 0);

  // 6. fc1 + exact gelu -> buf0 (bf16, ld 512)
  k_gemm_mfma<<<dim3(4, ROWS/128), 256, 0, stream>>>(
      buf1, 128, fc1T, fc1_b, buf0, 512, nullptr, nullptr, 128, 0, 1);

  // 7. fc2, accumulate into out (residual)
  k_gemm_mfma<<<dim3(1, ROWS/128), 256, 0, stream>>>(
      buf0, 512, fc2T, fc2_b, nullptr, 128, out, nullptr, 512, 2, 0);
}

// Round 4
// 321.803 us; speedup vs baseline: 3.4276x; 1.6180x over previous
//
#include <hip/hip_runtime.h>
#include <math.h>

#define ROWS 100352        // B * NW * N = 2*512*98
#define EPSL 1e-5f
#define SCALE_Q 0.17677669529663687f   // 32^-0.5

typedef __attribute__((ext_vector_type(8))) short bf16x8;
typedef __attribute__((ext_vector_type(4))) float f32x4;

__device__ __forceinline__ unsigned short f2b(float f) {
  union { float f; unsigned int u; } a; a.f = f;
  unsigned int u = a.u;
  return (unsigned short)((u + 0x7FFF + ((u >> 16) & 1)) >> 16);  // RNE
}
__device__ __forceinline__ float b2f(unsigned short s) {
  union { unsigned int u; float f; } a; a.u = ((unsigned int)s) << 16;
  return a.f;
}

// partition-row -> x flat spatial index (applies shift)
__device__ __forceinline__ size_t map_row(int r) {
  int t = r;
  int tw = t % 7; t /= 7;
  int th = t % 7; t /= 7;
  int td = t & 1;  t >>= 1;
  int zw = t & 7;  t >>= 3;
  int zh = t & 7;  t >>= 3;
  int zd = t & 7;  int bb = t >> 3;
  int d = zd * 2 + td;
  int h = zh * 7 + th;
  int w = zw * 7 + tw;
  int sd = (d + 1) & 15;
  int sh = h + 3; if (sh >= 56) sh -= 56;
  int sw = w + 3; if (sw >= 56) sw -= 56;
  return ((size_t)((bb * 16 + sd) * 56 + sh)) * 56 + sw;
}

// one combined prep: 4 weight transposes (W[K][N]->Wt[N][K] bf16) + bias table
__global__ __launch_bounds__(256) void k_prep_all(
    const float* __restrict__ qkv_w, unsigned short* __restrict__ qkvT,
    const float* __restrict__ proj_w, unsigned short* __restrict__ projT,
    const float* __restrict__ fc1_w, unsigned short* __restrict__ fc1T,
    const float* __restrict__ fc2_w, unsigned short* __restrict__ fc2T,
    const int* __restrict__ relidx, const float* __restrict__ rtab,
    float* __restrict__ biasTab)
{
  int b = blockIdx.x, tid = threadIdx.x;
  if (b < 192) {                      // qkvT: 128x384 -> [384][128]
    int id = b * 256 + tid;
    int n = id >> 7, k = id & 127;
    qkvT[id] = f2b(qkv_w[(size_t)k * 384 + n]);
  } else if (b < 256) {               // projT: [128][128]
    int id = (b - 192) * 256 + tid;
    int n = id >> 7, k = id & 127;
    projT[id] = f2b(proj_w[(size_t)k * 128 + n]);
  } else if (b < 512) {               // fc1T: [512][128]
    int id = (b - 256) * 256 + tid;
    int n = id >> 7, k = id & 127;
    fc1T[id] = f2b(fc1_w[(size_t)k * 512 + n]);
  } else if (b < 768) {               // fc2T: [128][512]
    int id = (b - 512) * 256 + tid;
    int n = id >> 9, k = id & 511;
    fc2T[id] = f2b(fc2_w[(size_t)k * 128 + n]);
  } else {                            // biasTab[h][e]
    int id = (b - 768) * 256 + tid;
    if (id < 9604) {
      int ri = relidx[id];
      #pragma unroll
      for (int h = 0; h < 4; ++h)
        biasTab[h * 9604 + id] = rtab[ri * 4 + h];
    }
  }
}

// ---- fused LN1 (+shift/partition gather) + qkv GEMM ----
// block: 128 rows; 4 waves 2x2; N=384 in 3 chunks of 128; B frags direct from L2.
__global__ __launch_bounds__(256) void k_qkv(
    const float* __restrict__ x, const float* __restrict__ g,
    const float* __restrict__ bta, const unsigned short* __restrict__ Wt,
    const float* __restrict__ bias, unsigned short* __restrict__ out)
{
  __shared__ unsigned short As[128 * 136];
  int tid = threadIdx.x;
  int row0 = blockIdx.x * 128;
  {
    int grp = tid >> 5, lane = tid & 31;
    float4 gv = *(const float4*)(g + lane*4);
    float4 bv = *(const float4*)(bta + lane*4);
    #pragma unroll
    for (int p = 0; p < 16; ++p) {
      int r = p * 8 + grp;
      size_t src = map_row(row0 + r);
      float4 v = *(const float4*)(x + src * 128 + lane * 4);
      float s  = v.x + v.y + v.z + v.w;
      float ss = v.x*v.x + v.y*v.y + v.z*v.z + v.w*v.w;
      #pragma unroll
      for (int o = 16; o; o >>= 1) {
        s  += __shfl_xor(s,  o, 32);
        ss += __shfl_xor(ss, o, 32);
      }
      float mu   = s * (1.f/128.f);
      float rstd = rsqrtf(ss * (1.f/128.f) - mu*mu + EPSL);
      ushort4 o4;
      o4.x = f2b((v.x-mu)*rstd*gv.x + bv.x);
      o4.y = f2b((v.y-mu)*rstd*gv.y + bv.y);
      o4.z = f2b((v.z-mu)*rstd*gv.z + bv.z);
      o4.w = f2b((v.w-mu)*rstd*gv.w + bv.w);
      *(ushort4*)&As[r*136 + lane*4] = o4;
    }
  }
  __syncthreads();
  int l = tid & 63, w = tid >> 6;
  int wr = (w >> 1) * 64, wc = (w & 1) * 64;
  int fr = l & 15, gq = l >> 4, fk = gq * 8;
  for (int c = 0; c < 3; ++c) {
    int col0 = c * 128;
    f32x4 acc[4][4] = {};
    #pragma unroll
    for (int ks = 0; ks < 128; ks += 32) {
      bf16x8 af[4], bv[4];
      #pragma unroll
      for (int m = 0; m < 4; ++m)
        af[m] = *(bf16x8*)&As[(wr + m*16 + fr)*136 + ks + fk];
      #pragma unroll
      for (int n = 0; n < 4; ++n)
        bv[n] = *(const bf16x8*)(Wt + (size_t)(col0 + wc + n*16 + fr)*128 + ks + fk);
      #pragma unroll
      for (int m = 0; m < 4; ++m)
        #pragma unroll
        for (int n = 0; n < 4; ++n)
          acc[m][n] = __builtin_amdgcn_mfma_f32_16x16x32_bf16(af[m], bv[n], acc[m][n], 0, 0, 0);
    }
    #pragma unroll
    for (int m = 0; m < 4; ++m)
      #pragma unroll
      for (int r = 0; r < 4; ++r) {
        int grow = row0 + wr + m*16 + gq*4 + r;
        #pragma unroll
        for (int n = 0; n < 4; ++n) {
          int col = col0 + wc + n*16 + fr;
          out[(size_t)grow*384 + col] = f2b(acc[m][n][r] + bias[col]);
        }
      }
  }
}

// ---- proj GEMM + window-reverse/unshift scatter + residual ----
__global__ __launch_bounds__(256) void k_proj(
    const unsigned short* __restrict__ A,       // (ROWS,128) bf16
    const unsigned short* __restrict__ Wt,      // (128,128) bf16
    const float* __restrict__ bias,
    const float* __restrict__ Xres, float* __restrict__ Cf)
{
  __shared__ unsigned short As[128 * 136];
  int tid = threadIdx.x;
  int row0 = blockIdx.x * 128;
  #pragma unroll
  for (int i = 0; i < 8; ++i) {
    int chunk = i * 256 + tid;
    int rr = chunk >> 4, off = (chunk & 15) * 8;
    *(uint4*)&As[rr*136 + off] = *(const uint4*)(A + (size_t)(row0+rr)*128 + off);
  }
  __syncthreads();
  int l = tid & 63, w = tid >> 6;
  int wr = (w >> 1) * 64, wc = (w & 1) * 64;
  int fr = l & 15, gq = l >> 4, fk = gq * 8;
  f32x4 acc[4][4] = {};
  #pragma unroll
  for (int ks = 0; ks < 128; ks += 32) {
    bf16x8 af[4], bv[4];
    #pragma unroll
    for (int m = 0; m < 4; ++m)
      af[m] = *(bf16x8*)&As[(wr + m*16 + fr)*136 + ks + fk];
    #pragma unroll
    for (int n = 0; n < 4; ++n)
      bv[n] = *(const bf16x8*)(Wt + (size_t)(wc + n*16 + fr)*128 + ks + fk);
    #pragma unroll
    for (int m = 0; m < 4; ++m)
      #pragma unroll
      for (int n = 0; n < 4; ++n)
        acc[m][n] = __builtin_amdgcn_mfma_f32_16x16x32_bf16(af[m], bv[n], acc[m][n], 0, 0, 0);
  }
  #pragma unroll
  for (int m = 0; m < 4; ++m)
    #pragma unroll
    for (int r = 0; r < 4; ++r) {
      int grow = row0 + wr + m*16 + gq*4 + r;
      size_t dst = map_row(grow);
      #pragma unroll
      for (int n = 0; n < 4; ++n) {
        int col = wc + n*16 + fr;
        Cf[dst*128 + col] = acc[m][n][r] + bias[col] + Xres[dst*128 + col];
      }
    }
}

// ---- fused LN2 + fc1 + exact-gelu + fc2 + residual accumulate ----
__global__ __launch_bounds__(256) void k_mlp(
    float* __restrict__ xio,                    // (ROWS,128) fp32, read+accum
    const float* __restrict__ g, const float* __restrict__ bta,
    const unsigned short* __restrict__ W1t,     // (512,128) bf16
    const float* __restrict__ b1,
    const unsigned short* __restrict__ W2t,     // (128,512) bf16
    const float* __restrict__ b2)
{
  __shared__ unsigned short As[128 * 136];
  __shared__ unsigned short Pb[128 * 136];
  int tid = threadIdx.x;
  int row0 = blockIdx.x * 128;
  {
    int grp = tid >> 5, lane = tid & 31;
    float4 gv = *(const float4*)(g + lane*4);
    float4 bv = *(const float4*)(bta + lane*4);
    #pragma unroll
    for (int p = 0; p < 16; ++p) {
      int r = p * 8 + grp;
      float4 v = *(const float4*)(xio + (size_t)(row0 + r) * 128 + lane * 4);
      float s  = v.x + v.y + v.z + v.w;
      float ss = v.x*v.x + v.y*v.y + v.z*v.z + v.w*v.w;
      #pragma unroll
      for (int o = 16; o; o >>= 1) {
        s  += __shfl_xor(s,  o, 32);
        ss += __shfl_xor(ss, o, 32);
      }
      float mu   = s * (1.f/128.f);
      float rstd = rsqrtf(ss * (1.f/128.f) - mu*mu + EPSL);
      ushort4 o4;
      o4.x = f2b((v.x-mu)*rstd*gv.x + bv.x);
      o4.y = f2b((v.y-mu)*rstd*gv.y + bv.y);
      o4.z = f2b((v.z-mu)*rstd*gv.z + bv.z);
      o4.w = f2b((v.w-mu)*rstd*gv.w + bv.w);
      *(ushort4*)&As[r*136 + lane*4] = o4;
    }
  }
  __syncthreads();
  int l = tid & 63, w = tid >> 6;
  int wr = (w >> 1) * 64, wc = (w & 1) * 64;
  int fr = l & 15, gq = l >> 4, fk = gq * 8;
  f32x4 O[4][4] = {};
  for (int j = 0; j < 4; ++j) {
    // fc1 chunk: S = A @ W1t[j*128 .. +128]^T
    f32x4 S[4][4] = {};
    #pragma unroll
    for (int ks = 0; ks < 128; ks += 32) {
      bf16x8 af[4], bv[4];
      #pragma unroll
      for (int m = 0; m < 4; ++m)
        af[m] = *(bf16x8*)&As[(wr + m*16 + fr)*136 + ks + fk];
      #pragma unroll
      for (int n = 0; n < 4; ++n)
        bv[n] = *(const bf16x8*)(W1t + (size_t)(j*128 + wc + n*16 + fr)*128 + ks + fk);
      #pragma unroll
      for (int m = 0; m < 4; ++m)
        #pragma unroll
        for (int n = 0; n < 4; ++n)
          S[m][n] = __builtin_amdgcn_mfma_f32_16x16x32_bf16(af[m], bv[n], S[m][n], 0, 0, 0);
    }
    // bias + exact gelu -> Pb
    #pragma unroll
    for (int m = 0; m < 4; ++m)
      #pragma unroll
      for (int n = 0; n < 4; ++n) {
        int col = wc + n*16 + fr;
        float bb = b1[j*128 + col];
        #pragma unroll
        for (int r = 0; r < 4; ++r) {
          float v = S[m][n][r] + bb;
          v = 0.5f * v * (1.f + erff(v * 0.7071067811865476f));
          Pb[(wr + m*16 + gq*4 + r)*136 + col] = f2b(v);
        }
      }
    __syncthreads();
    // fc2 chunk: O += P @ W2t[:, j*128 .. +128]^T
    #pragma unroll
    for (int ks = 0; ks < 128; ks += 32) {
      bf16x8 ap[4], bv[4];
      #pragma unroll
      for (int m = 0; m < 4; ++m)
        ap[m] = *(bf16x8*)&Pb[(wr + m*16 + fr)*136 + ks + fk];
      #pragma unroll
      for (int n = 0; n < 4; ++n)
        bv[n] = *(const bf16x8*)(W2t + (size_t)(wc + n*16 + fr)*512 + j*128 + ks + fk);
      #pragma unroll
      for (int m = 0; m < 4; ++m)
        #pragma unroll
        for (int n = 0; n < 4; ++n)
          O[m][n] = __builtin_amdgcn_mfma_f32_16x16x32_bf16(ap[m], bv[n], O[m][n], 0, 0, 0);
    }
    __syncthreads();
  }
  #pragma unroll
  for (int m = 0; m < 4; ++m)
    #pragma unroll
    for (int r = 0; r < 4; ++r) {
      size_t grow = row0 + wr + m*16 + gq*4 + r;
      #pragma unroll
      for (int n = 0; n < 4; ++n) {
        int col = wc + n*16 + fr;
        xio[grow*128 + col] += O[m][n][r] + b2[col];
      }
    }
}

// MFMA attention: one block per (window, head), 4 waves.
__global__ __launch_bounds__(256) void k_attn_mfma(
    const unsigned short* __restrict__ qkv,     // (ROWS, 384) bf16
    const float* __restrict__ biasTab,          // (4, 98, 98)
    unsigned short* __restrict__ o_part)        // (ROWS, 128) bf16
{
  __shared__ unsigned short Kb[112 * 40];
  __shared__ unsigned short Vt[32 * 136];
  __shared__ unsigned short Pb[128 * 136];
  __shared__ unsigned char cls[112];
  int tid  = threadIdx.x;
  int head = blockIdx.x & 3;
  int win  = blockIdx.x >> 2;
  int widx = win & 511;
  int zd = widx >> 6, zh = (widx >> 3) & 7, zw = widx & 7;
  int wmask = (zd == 7 ? 1 : 0) | (zh == 7 ? 2 : 0) | (zw == 7 ? 4 : 0);
  const unsigned short* base = qkv + (size_t)win * 98 * 384 + head * 32;

  for (int it = tid; it < 112 * 4; it += 256) {
    int n = it >> 2, c = (it & 3) << 3;
    bf16x8 kv = {0,0,0,0,0,0,0,0};
    if (n < 98) kv = *(const bf16x8*)(base + n*384 + 128 + c);
    *(bf16x8*)&Kb[n*40 + c] = kv;
  }
  for (int it = tid; it < 32 * 128; it += 256) {
    int d = it & 31, m = it >> 5;
    unsigned short v = 0;
    if (m < 98) v = base[m*384 + 256 + d];
    Vt[d*136 + m] = v;
  }
  for (int it = tid; it < 128 * 16; it += 256) {
    int n = it >> 4, c = 112 + (it & 15);
    Pb[n*136 + c] = 0;
  }
  if (tid < 112) {
    int i = tid;
    cls[i] = (unsigned char)((i >= 49 ? 1 : 0) |
                             (((i % 49) >= 28) ? 2 : 0) |
                             (((i % 7) >= 4) ? 4 : 0));
  }
  __syncthreads();

  int l = tid & 63, w = tid >> 6;
  int fr = l & 15, g = l >> 4;
  int fk = g * 8;

  bf16x8 aq[2];
  #pragma unroll
  for (int lt = 0; lt < 2; ++lt) {
    int row = (w*2 + lt)*16 + fr;
    bf16x8 q = {0,0,0,0,0,0,0,0};
    if (row < 98) q = *(const bf16x8*)(base + row*384 + fk);
    aq[lt] = q;
  }
  f32x4 S[2][7];
  #pragma unroll
  for (int ct = 0; ct < 7; ++ct) {
    bf16x8 b = *(bf16x8*)&Kb[(ct*16 + fr)*40 + fk];
    #pragma unroll
    for (int lt = 0; lt < 2; ++lt)
      S[lt][ct] = __builtin_amdgcn_mfma_f32_16x16x32_bf16(aq[lt], b, (f32x4){0.f,0.f,0.f,0.f}, 0, 0, 0);
  }

  const float* brow = biasTab + head * 9604;
  #pragma unroll
  for (int ct = 0; ct < 7; ++ct) {
    int m = ct*16 + fr;
    int cm = cls[m];
    #pragma unroll
    for (int lt = 0; lt < 2; ++lt) {
      #pragma unroll
      for (int r = 0; r < 4; ++r) {
        int n = w*32 + lt*16 + g*4 + r;
        float s = S[lt][ct][r] * SCALE_Q;
        if (m < 98) {
          if (n < 98) {
            s += brow[n*98 + m];
            if ((cls[n] ^ cm) & wmask) s -= 100.f;
          }
        } else {
          s = -1e30f;
        }
        S[lt][ct][r] = s;
      }
    }
  }

  #pragma unroll
  for (int lt = 0; lt < 2; ++lt) {
    #pragma unroll
    for (int r = 0; r < 4; ++r) {
      float mx = -1e30f;
      #pragma unroll
      for (int ct = 0; ct < 7; ++ct) mx = fmaxf(mx, S[lt][ct][r]);
      #pragma unroll
      for (int o = 8; o; o >>= 1) mx = fmaxf(mx, __shfl_xor(mx, o));
      float e[7], sum = 0.f;
      #pragma unroll
      for (int ct = 0; ct < 7; ++ct) { e[ct] = __expf(S[lt][ct][r] - mx); sum += e[ct]; }
      #pragma unroll
      for (int o = 8; o; o >>= 1) sum += __shfl_xor(sum, o);
      float inv = 1.f / sum;
      #pragma unroll
      for (int ct = 0; ct < 7; ++ct) S[lt][ct][r] = e[ct] * inv;
    }
  }

  #pragma unroll
  for (int lt = 0; lt < 2; ++lt)
    #pragma unroll
    for (int ct = 0; ct < 7; ++ct)
      #pragma unroll
      for (int r = 0; r < 4; ++r) {
        int n = w*32 + lt*16 + g*4 + r;
        int m = ct*16 + fr;
        Pb[n*136 + m] = f2b(S[lt][ct][r]);
      }
  __syncthreads();

  f32x4 O[2][2] = {};
  #pragma unroll
  for (int ks = 0; ks < 4; ++ks) {
    bf16x8 ap[2], bv[2];
    #pragma unroll
    for (int lt = 0; lt < 2; ++lt)
      ap[lt] = *(bf16x8*)&Pb[((w*2 + lt)*16 + fr)*136 + ks*32 + fk];
    #pragma unroll
    for (int vt = 0; vt < 2; ++vt)
      bv[vt] = *(bf16x8*)&Vt[(vt*16 + fr)*136 + ks*32 + fk];
    #pragma unroll
    for (int lt = 0; lt < 2; ++lt)
      #pragma unroll
      for (int vt = 0; vt < 2; ++vt)
        O[lt][vt] = __builtin_amdgcn_mfma_f32_16x16x32_bf16(ap[lt], bv[vt], O[lt][vt], 0, 0, 0);
  }

  #pragma unroll
  for (int lt = 0; lt < 2; ++lt)
    #pragma unroll
    for (int r = 0; r < 4; ++r) {
      int n = w*32 + lt*16 + g*4 + r;
      if (n < 98) {
        unsigned short* orow = o_part + ((size_t)win*98 + n)*128 + head*32;
        #pragma unroll
        for (int vt = 0; vt < 2; ++vt)
          orow[vt*16 + fr] = f2b(O[lt][vt][r]);
      }
    }
}

extern "C" void kernel_launch(void* const* d_in, const int* in_sizes, int n_in,
                              void* d_out, int out_size, void* d_ws, size_t ws_size,
                              hipStream_t stream)
{
  const float* x         = (const float*)d_in[0];
  const int*   rel_index = (const int*)  d_in[2];
  const float* n1g       = (const float*)d_in[3];
  const float* n1b       = (const float*)d_in[4];
  const float* qkv_w     = (const float*)d_in[5];
  const float* qkv_b     = (const float*)d_in[6];
  const float* rtab      = (const float*)d_in[7];
  const float* proj_w    = (const float*)d_in[8];
  const float* proj_b    = (const float*)d_in[9];
  const float* n2g       = (const float*)d_in[10];
  const float* n2b       = (const float*)d_in[11];
  const float* fc1_w     = (const float*)d_in[12];
  const float* fc1_b     = (const float*)d_in[13];
  const float* fc2_w     = (const float*)d_in[14];
  const float* fc2_b     = (const float*)d_in[15];
  float* out = (float*)d_out;

  // ws layout: buf0 ROWS*384 u16 (qkv), buf1 ROWS*128 u16 (attn out), weights, biasTab
  unsigned short* buf0  = (unsigned short*)d_ws;
  unsigned short* buf1  = buf0 + (size_t)ROWS * 384;
  unsigned short* qkvT  = buf1 + (size_t)ROWS * 128;
  unsigned short* projT = qkvT + 384 * 128;
  unsigned short* fc1T  = projT + 128 * 128;
  unsigned short* fc2T  = fc1T + 512 * 128;
  float* biasTab        = (float*)(fc2T + 128 * 512);

  // 0. weights transpose/convert + bias table (one launch)
  k_prep_all<<<806, 256, 0, stream>>>(qkv_w, qkvT, proj_w, projT, fc1_w, fc1T,
                                      fc2_w, fc2T, rel_index, rtab, biasTab);

  // 1. fused LN1+shift+partition+qkv -> buf0
  k_qkv<<<ROWS/128, 256, 0, stream>>>(x, n1g, n1b, qkvT, qkv_b, buf0);

  // 2. MFMA windowed attention -> buf1
  k_attn_mfma<<<4096, 256, 0, stream>>>(buf0, biasTab, buf1);

  // 3. proj + reverse/unshift scatter + residual -> out
  k_proj<<<ROWS/128, 256, 0, stream>>>(buf1, projT, proj_b, x, out);

  // 4. fused LN2 + fc1 + gelu + fc2 + residual -> out
  k_mlp<<<ROWS/128, 256, 0, stream>>>(out, n2g, n2b, fc1T, fc1_b, fc2T, fc2_b);
}

// Round 5
// 257.346 us; speedup vs baseline: 4.2861x; 1.2505x over previous
//
#include <hip/hip_runtime.h>
#include <math.h>

#define ROWS 100352        // B * NW * N = 2*512*98
#define EPSL 1e-5f
#define SCALE_Q 0.17677669529663687f   // 32^-0.5

typedef __attribute__((ext_vector_type(8))) short bf16x8;
typedef __attribute__((ext_vector_type(4))) float f32x4;

__device__ __forceinline__ unsigned short f2b(float f) {
  union { float f; unsigned int u; } a; a.f = f;
  unsigned int u = a.u;
  return (unsigned short)((u + 0x7FFF + ((u >> 16) & 1)) >> 16);  // RNE
}

// partition-row -> x flat spatial index (applies shift)
__device__ __forceinline__ size_t map_row(int r) {
  int t = r;
  int tw = t % 7; t /= 7;
  int th = t % 7; t /= 7;
  int td = t & 1;  t >>= 1;
  int zw = t & 7;  t >>= 3;
  int zh = t & 7;  t >>= 3;
  int zd = t & 7;  int bb = t >> 3;
  int d = zd * 2 + td;
  int h = zh * 7 + th;
  int w = zw * 7 + tw;
  int sd = (d + 1) & 15;
  int sh = h + 3; if (sh >= 56) sh -= 56;
  int sw = w + 3; if (sw >= 56) sw -= 56;
  return ((size_t)((bb * 16 + sd) * 56 + sh)) * 56 + sw;
}

// weight transposes (W[K][N] -> Wt[N][K] bf16); SCALE folded into Q columns of qkvT
__global__ __launch_bounds__(256) void k_prep_all(
    const float* __restrict__ qkv_w, unsigned short* __restrict__ qkvT,
    const float* __restrict__ proj_w, unsigned short* __restrict__ projT,
    const float* __restrict__ fc1_w, unsigned short* __restrict__ fc1T,
    const float* __restrict__ fc2_w, unsigned short* __restrict__ fc2T)
{
  int b = blockIdx.x, tid = threadIdx.x;
  if (b < 192) {                      // qkvT: [384][128]
    int id = b * 256 + tid;
    int n = id >> 7, k = id & 127;
    float v = qkv_w[(size_t)k * 384 + n];
    if (n < 128) v *= SCALE_Q;        // Q columns pre-scaled
    qkvT[id] = f2b(v);
  } else if (b < 256) {               // projT: [128][128]
    int id = (b - 192) * 256 + tid;
    int n = id >> 7, k = id & 127;
    projT[id] = f2b(proj_w[(size_t)k * 128 + n]);
  } else if (b < 512) {               // fc1T: [512][128]
    int id = (b - 256) * 256 + tid;
    int n = id >> 7, k = id & 127;
    fc1T[id] = f2b(fc1_w[(size_t)k * 512 + n]);
  } else {                            // fc2T: [128][512]
    int id = (b - 512) * 256 + tid;
    int n = id >> 9, k = id & 511;
    fc2T[id] = f2b(fc2_w[(size_t)k * 128 + n]);
  }
}

// biasC[wm][h][rt][ct][lane][4] : rel-bias + shift-mask + pad, in MFMA C-frag layout.
// C layout (16x16x32): row = (l>>4)*4 + r, col = l&15.
__global__ __launch_bounds__(256) void k_prep_biasC(
    const int* __restrict__ relidx, const float* __restrict__ rtab,
    float* __restrict__ biasC)
{
  int id = blockIdx.x * 256 + threadIdx.x;   // 8*4*8*7*64 = 114688
  int l  = id & 63;  int t = id >> 6;
  int ct = t % 7;    t /= 7;
  int rt = t & 7;    t >>= 3;
  int h  = t & 3;    int wm = t >> 2;
  int n0 = rt*16 + ((l >> 4) << 2);
  int m  = ct*16 + (l & 15);
  float4 v;
  float* vp = &v.x;
  int cm = 0;
  if (m < 98)
    cm = (m >= 49 ? 1 : 0) | ((m % 49) >= 28 ? 2 : 0) | ((m % 7) >= 4 ? 4 : 0);
  #pragma unroll
  for (int r = 0; r < 4; ++r) {
    int n = n0 + r;
    float val;
    if (m >= 98) val = -10000.f;
    else if (n >= 98) val = 0.f;
    else {
      val = rtab[relidx[n*98 + m]*4 + h];
      int cn = (n >= 49 ? 1 : 0) | ((n % 49) >= 28 ? 2 : 0) | ((n % 7) >= 4 ? 4 : 0);
      if ((cn ^ cm) & wm) val -= 100.f;
    }
    vp[r] = val;
  }
  *(float4*)(biasC + (size_t)id*4) = v;
}

// ---- fused LN1 (+shift/partition gather) + qkv GEMM ----
__global__ __launch_bounds__(256) void k_qkv(
    const float* __restrict__ x, const float* __restrict__ g,
    const float* __restrict__ bta, const unsigned short* __restrict__ Wt,
    const float* __restrict__ bias, unsigned short* __restrict__ out)
{
  __shared__ unsigned short As[128 * 136];
  int tid = threadIdx.x;
  int row0 = blockIdx.x * 128;
  {
    int grp = tid >> 5, lane = tid & 31;
    float4 gv = *(const float4*)(g + lane*4);
    float4 bv = *(const float4*)(bta + lane*4);
    #pragma unroll
    for (int p = 0; p < 16; ++p) {
      int r = p * 8 + grp;
      size_t src = map_row(row0 + r);
      float4 v = *(const float4*)(x + src * 128 + lane * 4);
      float s  = v.x + v.y + v.z + v.w;
      float ss = v.x*v.x + v.y*v.y + v.z*v.z + v.w*v.w;
      #pragma unroll
      for (int o = 16; o; o >>= 1) {
        s  += __shfl_xor(s,  o, 32);
        ss += __shfl_xor(ss, o, 32);
      }
      float mu   = s * (1.f/128.f);
      float rstd = rsqrtf(ss * (1.f/128.f) - mu*mu + EPSL);
      ushort4 o4;
      o4.x = f2b((v.x-mu)*rstd*gv.x + bv.x);
      o4.y = f2b((v.y-mu)*rstd*gv.y + bv.y);
      o4.z = f2b((v.z-mu)*rstd*gv.z + bv.z);
      o4.w = f2b((v.w-mu)*rstd*gv.w + bv.w);
      *(ushort4*)&As[r*136 + lane*4] = o4;
    }
  }
  __syncthreads();
  int l = tid & 63, w = tid >> 6;
  int wr = (w >> 1) * 64, wc = (w & 1) * 64;
  int fr = l & 15, gq = l >> 4, fk = gq * 8;
  for (int c = 0; c < 3; ++c) {
    int col0 = c * 128;
    float bmul = (c == 0) ? SCALE_Q : 1.f;   // Q bias pre-scaled to match weights
    f32x4 acc[4][4] = {};
    #pragma unroll
    for (int ks = 0; ks < 128; ks += 32) {
      bf16x8 af[4], bv[4];
      #pragma unroll
      for (int m = 0; m < 4; ++m)
        af[m] = *(bf16x8*)&As[(wr + m*16 + fr)*136 + ks + fk];
      #pragma unroll
      for (int n = 0; n < 4; ++n)
        bv[n] = *(const bf16x8*)(Wt + (size_t)(col0 + wc + n*16 + fr)*128 + ks + fk);
      #pragma unroll
      for (int m = 0; m < 4; ++m)
        #pragma unroll
        for (int n = 0; n < 4; ++n)
          acc[m][n] = __builtin_amdgcn_mfma_f32_16x16x32_bf16(af[m], bv[n], acc[m][n], 0, 0, 0);
    }
    #pragma unroll
    for (int m = 0; m < 4; ++m)
      #pragma unroll
      for (int r = 0; r < 4; ++r) {
        int grow = row0 + wr + m*16 + gq*4 + r;
        #pragma unroll
        for (int n = 0; n < 4; ++n) {
          int col = col0 + wc + n*16 + fr;
          out[(size_t)grow*384 + col] = f2b(acc[m][n][r] + bias[col]*bmul);
        }
      }
  }
}

// ---- proj GEMM + window-reverse/unshift scatter + residual ----
__global__ __launch_bounds__(256) void k_proj(
    const unsigned short* __restrict__ A,
    const unsigned short* __restrict__ Wt,
    const float* __restrict__ bias,
    const float* __restrict__ Xres, float* __restrict__ Cf)
{
  __shared__ unsigned short As[128 * 136];
  int tid = threadIdx.x;
  int row0 = blockIdx.x * 128;
  #pragma unroll
  for (int i = 0; i < 8; ++i) {
    int chunk = i * 256 + tid;
    int rr = chunk >> 4, off = (chunk & 15) * 8;
    *(uint4*)&As[rr*136 + off] = *(const uint4*)(A + (size_t)(row0+rr)*128 + off);
  }
  __syncthreads();
  int l = tid & 63, w = tid >> 6;
  int wr = (w >> 1) * 64, wc = (w & 1) * 64;
  int fr = l & 15, gq = l >> 4, fk = gq * 8;
  f32x4 acc[4][4] = {};
  #pragma unroll
  for (int ks = 0; ks < 128; ks += 32) {
    bf16x8 af[4], bv[4];
    #pragma unroll
    for (int m = 0; m < 4; ++m)
      af[m] = *(bf16x8*)&As[(wr + m*16 + fr)*136 + ks + fk];
    #pragma unroll
    for (int n = 0; n < 4; ++n)
      bv[n] = *(const bf16x8*)(Wt + (size_t)(wc + n*16 + fr)*128 + ks + fk);
    #pragma unroll
    for (int m = 0; m < 4; ++m)
      #pragma unroll
      for (int n = 0; n < 4; ++n)
        acc[m][n] = __builtin_amdgcn_mfma_f32_16x16x32_bf16(af[m], bv[n], acc[m][n], 0, 0, 0);
  }
  #pragma unroll
  for (int m = 0; m < 4; ++m)
    #pragma unroll
    for (int r = 0; r < 4; ++r) {
      int grow = row0 + wr + m*16 + gq*4 + r;
      size_t dst = map_row(grow);
      #pragma unroll
      for (int n = 0; n < 4; ++n) {
        int col = wc + n*16 + fr;
        Cf[dst*128 + col] = acc[m][n][r] + bias[col] + Xres[dst*128 + col];
      }
    }
}

// ---- fused LN2 + fc1 + gelu(tanh-form) + fc2 + residual accumulate ----
__global__ __launch_bounds__(256) void k_mlp(
    float* __restrict__ xio,
    const float* __restrict__ g, const float* __restrict__ bta,
    const unsigned short* __restrict__ W1t,
    const float* __restrict__ b1,
    const unsigned short* __restrict__ W2t,
    const float* __restrict__ b2)
{
  __shared__ unsigned short As[128 * 136];
  __shared__ unsigned short Pb[128 * 136];
  int tid = threadIdx.x;
  int row0 = blockIdx.x * 128;
  {
    int grp = tid >> 5, lane = tid & 31;
    float4 gv = *(const float4*)(g + lane*4);
    float4 bv = *(const float4*)(bta + lane*4);
    #pragma unroll
    for (int p = 0; p < 16; ++p) {
      int r = p * 8 + grp;
      float4 v = *(const float4*)(xio + (size_t)(row0 + r) * 128 + lane * 4);
      float s  = v.x + v.y + v.z + v.w;
      float ss = v.x*v.x + v.y*v.y + v.z*v.z + v.w*v.w;
      #pragma unroll
      for (int o = 16; o; o >>= 1) {
        s  += __shfl_xor(s,  o, 32);
        ss += __shfl_xor(ss, o, 32);
      }
      float mu   = s * (1.f/128.f);
      float rstd = rsqrtf(ss * (1.f/128.f) - mu*mu + EPSL);
      ushort4 o4;
      o4.x = f2b((v.x-mu)*rstd*gv.x + bv.x);
      o4.y = f2b((v.y-mu)*rstd*gv.y + bv.y);
      o4.z = f2b((v.z-mu)*rstd*gv.z + bv.z);
      o4.w = f2b((v.w-mu)*rstd*gv.w + bv.w);
      *(ushort4*)&As[r*136 + lane*4] = o4;
    }
  }
  __syncthreads();
  int l = tid & 63, w = tid >> 6;
  int wr = (w >> 1) * 64, wc = (w & 1) * 64;
  int fr = l & 15, gq = l >> 4, fk = gq * 8;
  f32x4 O[4][4] = {};
  for (int j = 0; j < 4; ++j) {
    f32x4 S[4][4] = {};
    #pragma unroll
    for (int ks = 0; ks < 128; ks += 32) {
      bf16x8 af[4], bv[4];
      #pragma unroll
      for (int m = 0; m < 4; ++m)
        af[m] = *(bf16x8*)&As[(wr + m*16 + fr)*136 + ks + fk];
      #pragma unroll
      for (int n = 0; n < 4; ++n)
        bv[n] = *(const bf16x8*)(W1t + (size_t)(j*128 + wc + n*16 + fr)*128 + ks + fk);
      #pragma unroll
      for (int m = 0; m < 4; ++m)
        #pragma unroll
        for (int n = 0; n < 4; ++n)
          S[m][n] = __builtin_amdgcn_mfma_f32_16x16x32_bf16(af[m], bv[n], S[m][n], 0, 0, 0);
    }
    #pragma unroll
    for (int m = 0; m < 4; ++m)
      #pragma unroll
      for (int n = 0; n < 4; ++n) {
        int col = wc + n*16 + fr;
        float bb = b1[j*128 + col];
        #pragma unroll
        for (int r = 0; r < 4; ++r) {
          float v = S[m][n][r] + bb;
          // gelu tanh-form: v * sigmoid(2*0.79788456*(v + 0.044715 v^3))
          float u = 1.5957691216057308f * v * (1.f + 0.044715f*v*v);
          v = v / (1.f + __expf(-u));
          Pb[(wr + m*16 + gq*4 + r)*136 + col] = f2b(v);
        }
      }
    __syncthreads();
    #pragma unroll
    for (int ks = 0; ks < 128; ks += 32) {
      bf16x8 ap[4], bv[4];
      #pragma unroll
      for (int m = 0; m < 4; ++m)
        ap[m] = *(bf16x8*)&Pb[(wr + m*16 + fr)*136 + ks + fk];
      #pragma unroll
      for (int n = 0; n < 4; ++n)
        bv[n] = *(const bf16x8*)(W2t + (size_t)(wc + n*16 + fr)*512 + j*128 + ks + fk);
      #pragma unroll
      for (int m = 0; m < 4; ++m)
        #pragma unroll
        for (int n = 0; n < 4; ++n)
          O[m][n] = __builtin_amdgcn_mfma_f32_16x16x32_bf16(ap[m], bv[n], O[m][n], 0, 0, 0);
    }
    __syncthreads();
  }
  #pragma unroll
  for (int m = 0; m < 4; ++m)
    #pragma unroll
    for (int r = 0; r < 4; ++r) {
      size_t grow = row0 + wr + m*16 + gq*4 + r;
      #pragma unroll
      for (int n = 0; n < 4; ++n) {
        int col = wc + n*16 + fr;
        xio[grow*128 + col] += O[m][n][r] + b2[col];
      }
    }
}

// MFMA attention v2: bias/mask/scale baked into biasC (C-frag layout);
// K/Q frags direct from global; one barrier; 39.4 KB LDS -> 4 blocks/CU.
__global__ __launch_bounds__(256, 4) void k_attn_mfma(
    const unsigned short* __restrict__ qkv,     // (ROWS, 384) bf16, Q pre-scaled
    const float* __restrict__ biasC,            // [8][4][8][7][64][4] f32
    unsigned short* __restrict__ o_part)        // (ROWS, 128) bf16
{
  __shared__ unsigned short Vt[32 * 136];   // [d][m], m 0..127 (>=98 zero)
  __shared__ unsigned short Pb[128 * 120];  // [n][m], m 0..119 (112..119 zero)
  int tid  = threadIdx.x;
  int head = blockIdx.x & 3;
  int win  = blockIdx.x >> 2;
  int widx = win & 511;
  int wm = ((widx >> 6) == 7 ? 1 : 0) | (((widx >> 3) & 7) == 7 ? 2 : 0)
         | ((widx & 7) == 7 ? 4 : 0);
  const unsigned short* base = qkv + (size_t)win * 98 * 384 + head * 32;

  // stage V transposed (consumed only after the single barrier below)
  for (int it = tid; it < 32 * 128; it += 256) {
    int d = it & 31, m = it >> 5;
    unsigned short v = 0;
    if (m < 98) v = base[m*384 + 256 + d];
    Vt[d*136 + m] = v;
  }
  for (int it = tid; it < 128 * 8; it += 256) {
    int n = it >> 3, c2 = 112 + (it & 7);
    Pb[n*120 + c2] = 0;
  }

  int l = tid & 63, w = tid >> 6;
  int fr = l & 15, g = l >> 4, fk = g * 8;
  bf16x8 zero8 = {0,0,0,0,0,0,0,0};

  // Q fragments (rows >=98 zeroed)
  bf16x8 aq[2];
  #pragma unroll
  for (int lt = 0; lt < 2; ++lt) {
    int row = (w*2 + lt)*16 + fr;
    aq[lt] = (row < 98) ? *(const bf16x8*)(base + row*384 + fk) : zero8;
  }

  // QK^T with bias-initialized accumulator
  const float* bcb = biasC + (size_t)(wm*4 + head) * 8 * 7 * 256;
  f32x4 S[2][7];
  #pragma unroll
  for (int ct = 0; ct < 7; ++ct) {
    int m = ct*16 + fr;
    bf16x8 kb = (m < 98) ? *(const bf16x8*)(base + m*384 + 128 + fk) : zero8;
    #pragma unroll
    for (int lt = 0; lt < 2; ++lt) {
      f32x4 bc = *(const f32x4*)(bcb + ((w*2 + lt)*7 + ct)*256 + l*4);
      S[lt][ct] = __builtin_amdgcn_mfma_f32_16x16x32_bf16(aq[lt], kb, bc, 0, 0, 0);
    }
  }

  // softmax per row (cols live in 16 fr-lanes x 7 regs)
  #pragma unroll
  for (int lt = 0; lt < 2; ++lt) {
    #pragma unroll
    for (int r = 0; r < 4; ++r) {
      float mx = S[lt][0][r];
      #pragma unroll
      for (int ct = 1; ct < 7; ++ct) mx = fmaxf(mx, S[lt][ct][r]);
      #pragma unroll
      for (int o = 8; o; o >>= 1) mx = fmaxf(mx, __shfl_xor(mx, o));
      float e[7], sum = 0.f;
      #pragma unroll
      for (int ct = 0; ct < 7; ++ct) { e[ct] = __expf(S[lt][ct][r] - mx); sum += e[ct]; }
      #pragma unroll
      for (int o = 8; o; o >>= 1) sum += __shfl_xor(sum, o);
      float inv = 1.f / sum;
      #pragma unroll
      for (int ct = 0; ct < 7; ++ct) S[lt][ct][r] = e[ct] * inv;
    }
  }

  // P -> LDS
  #pragma unroll
  for (int lt = 0; lt < 2; ++lt)
    #pragma unroll
    for (int ct = 0; ct < 7; ++ct) {
      int m = ct*16 + fr;
      #pragma unroll
      for (int r = 0; r < 4; ++r) {
        int n = w*32 + lt*16 + g*4 + r;
        Pb[n*120 + m] = f2b(S[lt][ct][r]);
      }
    }
  __syncthreads();

  // PV: K=128 in 4 x32 slices; last slice's A-cols 120..127 don't exist -> zero frag
  f32x4 O[2][2] = {};
  #pragma unroll
  for (int ks = 0; ks < 4; ++ks) {
    bf16x8 ap[2], bv[2];
    #pragma unroll
    for (int lt = 0; lt < 2; ++lt) {
      int rowoff = ((w*2 + lt)*16 + fr)*120;
      if (ks < 3) ap[lt] = *(bf16x8*)&Pb[rowoff + ks*32 + fk];
      else        ap[lt] = (g < 2) ? *(bf16x8*)&Pb[rowoff + 96 + fk] : zero8;
    }
    #pragma unroll
    for (int vt = 0; vt < 2; ++vt)
      bv[vt] = *(bf16x8*)&Vt[(vt*16 + fr)*136 + ks*32 + fk];
    #pragma unroll
    for (int lt = 0; lt < 2; ++lt)
      #pragma unroll
      for (int vt = 0; vt < 2; ++vt)
        O[lt][vt] = __builtin_amdgcn_mfma_f32_16x16x32_bf16(ap[lt], bv[vt], O[lt][vt], 0, 0, 0);
  }

  #pragma unroll
  for (int lt = 0; lt < 2; ++lt)
    #pragma unroll
    for (int r = 0; r < 4; ++r) {
      int n = w*32 + lt*16 + g*4 + r;
      if (n < 98) {
        unsigned short* orow = o_part + ((size_t)win*98 + n)*128 + head*32;
        #pragma unroll
        for (int vt = 0; vt < 2; ++vt)
          orow[vt*16 + fr] = f2b(O[lt][vt][r]);
      }
    }
}

extern "C" void kernel_launch(void* const* d_in, const int* in_sizes, int n_in,
                              void* d_out, int out_size, void* d_ws, size_t ws_size,
                              hipStream_t stream)
{
  const float* x         = (const float*)d_in[0];
  const int*   rel_index = (const int*)  d_in[2];
  const float* n1g       = (const float*)d_in[3];
  const float* n1b       = (const float*)d_in[4];
  const float* qkv_w     = (const float*)d_in[5];
  const float* qkv_b     = (const float*)d_in[6];
  const float* rtab      = (const float*)d_in[7];
  const float* proj_w    = (const float*)d_in[8];
  const float* proj_b    = (const float*)d_in[9];
  const float* n2g       = (const float*)d_in[10];
  const float* n2b       = (const float*)d_in[11];
  const float* fc1_w     = (const float*)d_in[12];
  const float* fc1_b     = (const float*)d_in[13];
  const float* fc2_w     = (const float*)d_in[14];
  const float* fc2_b     = (const float*)d_in[15];
  float* out = (float*)d_out;

  unsigned short* buf0  = (unsigned short*)d_ws;          // ROWS*384
  unsigned short* buf1  = buf0 + (size_t)ROWS * 384;      // ROWS*128
  unsigned short* qkvT  = buf1 + (size_t)ROWS * 128;
  unsigned short* projT = qkvT + 384 * 128;
  unsigned short* fc1T  = projT + 128 * 128;
  unsigned short* fc2T  = fc1T + 512 * 128;
  float* biasC          = (float*)(fc2T + 128 * 512);     // 458752 f32

  // 0. weights transpose/convert + attention bias fragments
  k_prep_all<<<768, 256, 0, stream>>>(qkv_w, qkvT, proj_w, projT,
                                      fc1_w, fc1T, fc2_w, fc2T);
  k_prep_biasC<<<448, 256, 0, stream>>>(rel_index, rtab, biasC);

  // 1. fused LN1+shift+partition+qkv -> buf0
  k_qkv<<<ROWS/128, 256, 0, stream>>>(x, n1g, n1b, qkvT, qkv_b, buf0);

  // 2. MFMA windowed attention -> buf1
  k_attn_mfma<<<4096, 256, 0, stream>>>(buf0, biasC, buf1);

  // 3. proj + reverse/unshift scatter + residual -> out
  k_proj<<<ROWS/128, 256, 0, stream>>>(buf1, projT, proj_b, x, out);

  // 4. fused LN2 + fc1 + gelu + fc2 + residual -> out
  k_mlp<<<ROWS/128, 256, 0, stream>>>(out, n2g, n2b, fc1T, fc1_b, fc2T, fc2_b);
}